// Round 1
// baseline (447.938 us; speedup 1.0000x reference)
//
#include <hip/hip_runtime.h>
#include <math.h>

#define N_NODES    100000
#define K_NEIGH    32
#define OUT_STRIDE 448   // 3*128 + 64

typedef __attribute__((ext_vector_type(8))) __bf16 bf16x8;
typedef __attribute__((ext_vector_type(4))) float  f32x4;

// bf16 helpers (RNE)
static __device__ __forceinline__ unsigned short f2bf(float f) {
    unsigned int u = __float_as_uint(f);
    return (unsigned short)((u + 0x7FFFu + ((u >> 16) & 1u)) >> 16);
}
static __device__ __forceinline__ float bf2f(unsigned short h) {
    return __uint_as_float(((unsigned int)h) << 16);
}

// ---------------------------------------------------------------------------
// One-shot prep: iw[n][k] = (idx[n][k], bits(exp(-10*dist[n][k])))  -- fused
// neighbor/weight table so the acc hot loop does ONE dwordx2 per k instead of
// two dependent loads. Also bf16 transposed weights for the MFMA dense.
// ---------------------------------------------------------------------------
__global__ __launch_bounds__(256) void prep_kernel(
    const float* __restrict__ dist, const int* __restrict__ idx,
    int2* __restrict__ iw,
    const float* __restrict__ W0, const float* __restrict__ W1,
    const float* __restrict__ W2,
    unsigned short* __restrict__ Wt0, unsigned short* __restrict__ Wt1,
    unsigned short* __restrict__ Wt2)
{
    const int i = blockIdx.x * 256 + threadIdx.x;
    if (i < N_NODES * K_NEIGH)
        iw[i] = make_int2(idx[i], __float_as_int(__expf(-10.f * dist[i])));
    if (i < 64 * 64)  Wt0[(i & 63) * 64  + (i >> 6)] = f2bf(W0[i]);  // i = k*64+n
    if (i < 128 * 64) Wt1[(i & 63) * 128 + (i >> 6)] = f2bf(W1[i]);
    if (i < 128 * 64) Wt2[(i & 63) * 128 + (i >> 6)] = f2bf(W2[i]);
}

// ---------------------------------------------------------------------------
// Dense layer via MFMA: F[n][c] = relu(b[c] + sum_k in[n][k]*W[k][c]), bf16 out.
// (unchanged from previous round — ~12 us each, not the bottleneck)
// ---------------------------------------------------------------------------
template <int DIN, bool COPY_X>
__global__ __launch_bounds__(256) void dense_kernel(
    const float* __restrict__ in, int in_stride,
    const unsigned short* __restrict__ Wt,   // [64][DIN] bf16 (transposed W)
    const float* __restrict__ b,
    unsigned short* __restrict__ F, float* __restrict__ out)
{
    constexpr int LDK = DIN + 8;
    __shared__ unsigned short aLDS[64 * LDK];
    __shared__ unsigned short bLDS[64 * LDK];

    const int tid  = threadIdx.x;
    const int row0 = blockIdx.x * 64;

    // Stage A: 64 rows x DIN fp32 -> bf16 (coalesced float4 reads)
    for (int i = tid; i < 64 * (DIN / 4); i += 256) {
        const int r = i / (DIN / 4);
        const int c = (i % (DIN / 4)) * 4;
        const int n = row0 + r;
        float4 v = make_float4(0.f, 0.f, 0.f, 0.f);
        if (n < N_NODES) {
            v = *(const float4*)&in[(size_t)n * in_stride + c];
            if (COPY_X) *(float4*)&out[(size_t)n * OUT_STRIDE + 384 + c] = v;
        }
        const unsigned int u0 = (unsigned int)f2bf(v.x) | ((unsigned int)f2bf(v.y) << 16);
        const unsigned int u1 = (unsigned int)f2bf(v.z) | ((unsigned int)f2bf(v.w) << 16);
        *(uint2*)&aLDS[r * LDK + c] = make_uint2(u0, u1);
    }
    // Stage B: Wt [64][DIN] bf16 -> padded LDS (b128 copies)
    for (int i = tid; i < 64 * (DIN / 8); i += 256) {
        const int nn = i / (DIN / 8);
        const int k0 = (i % (DIN / 8)) * 8;
        *(uint4*)&bLDS[nn * LDK + k0] = *(const uint4*)&Wt[nn * DIN + k0];
    }
    __syncthreads();

    const int lane = tid & 63;
    const int wv   = tid >> 6;
    const int m    = lane & 15;
    const int quad = lane >> 4;

    f32x4 acc[4];
#pragma unroll
    for (int nb = 0; nb < 4; ++nb) acc[nb] = (f32x4){0.f, 0.f, 0.f, 0.f};

#pragma unroll
    for (int ks = 0; ks < DIN / 32; ++ks) {
        const int koff = ks * 32 + quad * 8;
        const bf16x8 afr =
            *reinterpret_cast<const bf16x8*>(&aLDS[(wv * 16 + m) * LDK + koff]);
#pragma unroll
        for (int nb = 0; nb < 4; ++nb) {
            const bf16x8 bfr =
                *reinterpret_cast<const bf16x8*>(&bLDS[(nb * 16 + m) * LDK + koff]);
            acc[nb] = __builtin_amdgcn_mfma_f32_16x16x32_bf16(afr, bfr, acc[nb], 0, 0, 0);
        }
    }

    // Epilogue: bias + relu + bf16 store
#pragma unroll
    for (int nb = 0; nb < 4; ++nb) {
        const int c    = nb * 16 + m;
        const float bc = b[c];
#pragma unroll
        for (int reg = 0; reg < 4; ++reg) {
            const int n = row0 + wv * 16 + quad * 4 + reg;
            if (n < N_NODES) {
                const float vv = fmaxf(acc[nb][reg] + bc, 0.f);
                F[(size_t)n * 64 + c] = f2bf(vv);
            }
        }
    }
}

// ---------------------------------------------------------------------------
// KNN accumulate, v2: 8 nodes per wave, dwordx4 gathers.
//   lane layout: g = lane>>3 (node within wave, 8 nodes), cp = lane&7
//   (channel slice: channels [cp*8, cp*8+8), 16 B of bf16).
// Per k: one dwordx2 (fused idx,w pair — broadcast within the 8-lane group,
// L1-resident line across k) + ONE dwordx4 gather delivering 8 full F rows
// (1 KB) per wave instruction — 8x fewer VMEM instructions than the
// ushort-per-lane version, no scalar-load address dependency chain.
// Out stores are nontemporal so 51 MB/layer of write-allocate doesn't evict
// the gather-hot F working set from L2.
// ---------------------------------------------------------------------------
__global__ __launch_bounds__(256) void acc_kernel(
    const unsigned short* __restrict__ F,
    const int2* __restrict__ iw,
    float* __restrict__ out)   // already offset to this layer's slab
{
    const int tid  = threadIdx.x;
    const int lane = tid & 63;
    const int wv   = tid >> 6;
    const int g    = lane >> 3;   // node in wave: 0..7
    const int cp   = lane & 7;    // channel part: 8 channels each
    const int n    = blockIdx.x * 32 + wv * 8 + g;

    // prev = F[n][cp*8 .. cp*8+8)
    const uint4 pv = *(const uint4*)&F[(size_t)n * 64 + cp * 8];

    float sum[8], mx[8];
#pragma unroll
    for (int j = 0; j < 8; ++j) { sum[j] = 0.f; mx[j] = -INFINITY; }

    const int2* __restrict__ iwrow = iw + (size_t)n * K_NEIGH;

#pragma unroll 8
    for (int k = 0; k < K_NEIGH; ++k) {
        const int2  p  = iwrow[k];                 // (neighbor, weight-bits)
        const float wk = __int_as_float(p.y);
        const uint4 gv = *(const uint4*)&F[(size_t)p.x * 64 + cp * 8];
#pragma unroll
        for (int d = 0; d < 4; ++d) {
            const unsigned int u = (&gv.x)[d];
            const float glo = __uint_as_float(u << 16);
            const float ghi = __uint_as_float(u & 0xffff0000u);
            const float t0 = wk * glo;
            const float t1 = wk * ghi;
            sum[2 * d]     += t0;
            sum[2 * d + 1] += t1;
            mx[2 * d]      = fmaxf(mx[2 * d], t0);
            mx[2 * d + 1]  = fmaxf(mx[2 * d + 1], t1);
        }
    }

    // unpack prev
    float pvf[8];
#pragma unroll
    for (int d = 0; d < 4; ++d) {
        const unsigned int u = (&pv.x)[d];
        pvf[2 * d]     = __uint_as_float(u << 16);
        pvf[2 * d + 1] = __uint_as_float(u & 0xffff0000u);
    }

    float* orow = out + (size_t)n * OUT_STRIDE + cp * 8;
    const float s = 1.f / 32.f;
    f32x4 m0 = {sum[0] * s - pvf[0], sum[1] * s - pvf[1],
                sum[2] * s - pvf[2], sum[3] * s - pvf[3]};
    f32x4 m1 = {sum[4] * s - pvf[4], sum[5] * s - pvf[5],
                sum[6] * s - pvf[6], sum[7] * s - pvf[7]};
    f32x4 x0 = {mx[0] - pvf[0], mx[1] - pvf[1], mx[2] - pvf[2], mx[3] - pvf[3]};
    f32x4 x1 = {mx[4] - pvf[4], mx[5] - pvf[5], mx[6] - pvf[6], mx[7] - pvf[7]};
    __builtin_nontemporal_store(m0, (f32x4*)(orow + 0));
    __builtin_nontemporal_store(m1, (f32x4*)(orow + 4));
    __builtin_nontemporal_store(x0, (f32x4*)(orow + 64));
    __builtin_nontemporal_store(x1, (f32x4*)(orow + 68));
}

// ---------------------------------------------------------------------------
extern "C" void kernel_launch(void* const* d_in, const int* in_sizes, int n_in,
                              void* d_out, int out_size, void* d_ws, size_t ws_size,
                              hipStream_t stream)
{
    const float* x    = (const float*)d_in[0];
    const int*   idx  = (const int*)  d_in[1];
    const float* dist = (const float*)d_in[2];
    const float* W0   = (const float*)d_in[3];
    const float* b0   = (const float*)d_in[4];
    const float* W1   = (const float*)d_in[5];
    const float* b1   = (const float*)d_in[6];
    const float* W2   = (const float*)d_in[7];
    const float* b2   = (const float*)d_in[8];

    float* out = (float*)d_out;

    // Workspace layout (all 16B-aligned):
    char* ws = (char*)d_ws;
    unsigned short* F   = (unsigned short*)(ws);                 // 12.8 MB
    int2*           iw  = (int2*)          (ws + 12800000);      // 25.6 MB
    unsigned short* Wt0 = (unsigned short*)(ws + 38400000);      // 8 KB
    unsigned short* Wt1 = (unsigned short*)(ws + 38408192);      // 16 KB
    unsigned short* Wt2 = (unsigned short*)(ws + 38424576);      // 16 KB

    const int prep_grid  = (N_NODES * K_NEIGH + 255) / 256;  // 12500
    const int dense_grid = (N_NODES + 63) / 64;              // 1563
    const int acc_grid   = N_NODES / 32;                     // 3125

    prep_kernel<<<prep_grid, 256, 0, stream>>>(dist, idx, iw, W0, W1, W2, Wt0, Wt1, Wt2);

    // Layer 0: dense from x (also copies x into out[:,384:448])
    dense_kernel<64, true><<<dense_grid, 256, 0, stream>>>(x, 64, Wt0, b0, F, out);
    acc_kernel<<<acc_grid, 256, 0, stream>>>(F, iw, out + 0);

    // Layer 1: dense reads layer-0 slab of out (it IS the next input)
    dense_kernel<128, false><<<dense_grid, 256, 0, stream>>>(out + 0, OUT_STRIDE, Wt1, b1, F, nullptr);
    acc_kernel<<<acc_grid, 256, 0, stream>>>(F, iw, out + 128);

    // Layer 2
    dense_kernel<128, false><<<dense_grid, 256, 0, stream>>>(out + 128, OUT_STRIDE, Wt2, b2, F, nullptr);
    acc_kernel<<<acc_grid, 256, 0, stream>>>(F, iw, out + 256);
}